// Round 1
// baseline (29.779 us; speedup 1.0000x reference)
//
#include <hip/hip_runtime.h>

// JaggedAppend: out = concat_i( values[seg_i] ++ suffix_mat[i] )
// One block per segment. prefix_sum is the INCLUSIVE prefix sum of old
// segment lengths (int32 after JAX's x64 downcast). Output segment i starts
// at prefix_sum[i-1] + i*SUF in out.

#define SUF 256

__global__ void jagged_append_kernel(const float* __restrict__ values,
                                     const int* __restrict__ prefix_sum,
                                     const float* __restrict__ suffix,
                                     float* __restrict__ out,
                                     int B) {
    const int seg = blockIdx.x;
    if (seg >= B) return;

    const long long prev_old = (seg > 0) ? (long long)prefix_sum[seg - 1] : 0ll;
    const long long end_old  = (long long)prefix_sum[seg];
    const long long seg_len  = end_old - prev_old;
    const long long new_start = prev_old + (long long)seg * SUF;

    // Copy old values slice (coalesced grid-stride within block).
    for (long long i = threadIdx.x; i < seg_len; i += blockDim.x) {
        out[new_start + i] = values[prev_old + i];
    }

    // Copy suffix row (256 elements, one per thread with block=256).
    const float* sfx = suffix + (long long)seg * SUF;
    const long long suf_base = new_start + seg_len;
    for (int i = threadIdx.x; i < SUF; i += blockDim.x) {
        out[suf_base + i] = sfx[i];
    }
}

extern "C" void kernel_launch(void* const* d_in, const int* in_sizes, int n_in,
                              void* d_out, int out_size, void* d_ws, size_t ws_size,
                              hipStream_t stream) {
    const float* values     = (const float*)d_in[0];
    const int*   prefix_sum = (const int*)d_in[1];
    const float* suffix     = (const float*)d_in[2];
    float* out = (float*)d_out;

    const int B = in_sizes[1];  // 8192 segments

    jagged_append_kernel<<<B, 256, 0, stream>>>(values, prefix_sum, suffix, out, B);
}

// Round 2
// 28.976 us; speedup vs baseline: 1.0277x; 1.0277x over previous
//
#include <hip/hip_runtime.h>

// JaggedAppend: out = concat_i( values[seg_i] ++ suffix_mat[i] )
// One block per segment. prefix_sum is the INCLUSIVE prefix sum of old
// segment lengths (int32). Output segment i starts at prefix_sum[i-1]+i*SUF.
//
// Vectorization: new_start - prev_old = seg*SUF (SUF=256 floats = 1024 B),
// so src (values+prev_old) and dst (out+new_start) have identical alignment
// phase mod 16 B. One shared scalar head of <=3 elems aligns both, then the
// interior is aligned float4 on both sides.

#define SUF 256

__global__ void jagged_append_kernel(const float* __restrict__ values,
                                     const int* __restrict__ prefix_sum,
                                     const float* __restrict__ suffix,
                                     float* __restrict__ out,
                                     int B) {
    const int seg = blockIdx.x;
    if (seg >= B) return;
    const int tid = threadIdx.x;
    const int nthr = blockDim.x;

    const long long prev_old = (seg > 0) ? (long long)prefix_sum[seg - 1] : 0ll;
    const long long end_old  = (long long)prefix_sum[seg];
    const long long seg_len  = end_old - prev_old;
    const long long new_start = prev_old + (long long)seg * SUF;

    const float* __restrict__ src = values + prev_old;
    float* __restrict__ dst = out + new_start;

    // Scalar head to reach 16B alignment (same phase on src and dst).
    long long head = (4 - (new_start & 3)) & 3;
    if (head > seg_len) head = seg_len;
    if (tid < head) dst[tid] = src[tid];

    // Aligned float4 interior.
    const long long nvec = (seg_len - head) >> 2;
    const float4* __restrict__ vsrc = (const float4*)(src + head);
    float4* __restrict__ vdst = (float4*)(dst + head);
    for (long long v = tid; v < nvec; v += nthr) {
        vdst[v] = vsrc[v];
    }

    // Scalar tail (<=3 elems).
    const long long tail_start = head + (nvec << 2);
    for (long long i = tail_start + tid; i < seg_len; i += nthr) {
        dst[i] = src[i];
    }

    // Suffix row: 256 floats, src aligned but dst phase arbitrary -> scalar.
    const float* __restrict__ sfx = suffix + (long long)seg * SUF;
    float* __restrict__ sdst = dst + seg_len;
    for (int i = tid; i < SUF; i += nthr) {
        sdst[i] = sfx[i];
    }
}

extern "C" void kernel_launch(void* const* d_in, const int* in_sizes, int n_in,
                              void* d_out, int out_size, void* d_ws, size_t ws_size,
                              hipStream_t stream) {
    const float* values     = (const float*)d_in[0];
    const int*   prefix_sum = (const int*)d_in[1];
    const float* suffix     = (const float*)d_in[2];
    float* out = (float*)d_out;

    const int B = in_sizes[1];  // 8192 segments

    jagged_append_kernel<<<B, 256, 0, stream>>>(values, prefix_sum, suffix, out, B);
}